// Round 2
// baseline (191.435 us; speedup 1.0000x reference)
//
#include <hip/hip_runtime.h>
#include <hip/hip_bf16.h>
#include <stdint.h>

typedef __bf16 bf16;
typedef __attribute__((ext_vector_type(8))) __bf16 bf16x8;
typedef __attribute__((ext_vector_type(4))) float f32x4;
typedef __attribute__((ext_vector_type(16))) float f32x16;

#define SEQ   2048
#define HEADS 8
#define CDIM  512
// C2 = SCALE * log2(e) = 0.125 * 1.4426950408889634
#define C2      0.18033688011112043f
#define THR_RAW 44.3614f   /* 8 / C2 : defer-max threshold in raw-score units */

__device__ __forceinline__ void glds16(const bf16* g, bf16* l) {
    __builtin_amdgcn_global_load_lds((const __attribute__((address_space(1))) void*)g,
                                     (__attribute__((address_space(3))) void*)l, 16, 0, 0);
}
__device__ __forceinline__ uint32_t pk_bf16(float a, float b) {
    uint32_t r; asm("v_cvt_pk_bf16_f32 %0, %1, %2" : "=v"(r) : "v"(a), "v"(b)); return r;
}
__device__ __forceinline__ void pl_swap(uint32_t &a, uint32_t &b) {
    asm("v_permlane32_swap_b32 %0, %1" : "+v"(a), "+v"(b));
}
__device__ __forceinline__ void wait_vm4() { asm volatile("s_waitcnt vmcnt(4)" ::: "memory"); }
__device__ __forceinline__ void wait_vm3() { asm volatile("s_waitcnt vmcnt(3)" ::: "memory"); }
__device__ __forceinline__ void wait_vm0() { asm volatile("s_waitcnt vmcnt(0)" ::: "memory"); }

// ---------------------------------------------------------------------------
// 1) hs fp32 -> bf16
__global__ __launch_bounds__(256) void k_cvt_hs(const float* __restrict__ in,
                                                bf16* __restrict__ out) {
    int idx = blockIdx.x * 256 + threadIdx.x;
    const float4* in4 = reinterpret_cast<const float4*>(in);
    float4 a = in4[idx * 2], b = in4[idx * 2 + 1];
    bf16x8 o;
    o[0] = (bf16)a.x; o[1] = (bf16)a.y; o[2] = (bf16)a.z; o[3] = (bf16)a.w;
    o[4] = (bf16)b.x; o[5] = (bf16)b.y; o[6] = (bf16)b.z; o[7] = (bf16)b.w;
    reinterpret_cast<bf16x8*>(out)[idx] = o;
}

// ---------------------------------------------------------------------------
// 2) weight transpose+convert: W[fin][fout] f32 -> Wt[fout][fin] bf16 (4 mats)
__global__ __launch_bounds__(256) void k_wtrans(const float* __restrict__ w0,
                                                const float* __restrict__ w1,
                                                const float* __restrict__ w2,
                                                const float* __restrict__ w3,
                                                bf16* __restrict__ wt) {
    const float* w = blockIdx.z == 0 ? w0 : blockIdx.z == 1 ? w1 : blockIdx.z == 2 ? w2 : w3;
    bf16* out = wt + (size_t)blockIdx.z * CDIM * CDIM;
    __shared__ bf16 tile[64][65];
    const int t = threadIdx.x;
    const int r0 = blockIdx.x * 64, c0 = blockIdx.y * 64;
    const int r = t >> 2, cc = (t & 3) * 16;
    const float4* src = reinterpret_cast<const float4*>(w + (size_t)(r0 + r) * CDIM + c0 + cc);
#pragma unroll
    for (int v = 0; v < 4; ++v) {
        float4 f = src[v];
        tile[r][cc + v * 4 + 0] = (bf16)f.x;
        tile[r][cc + v * 4 + 1] = (bf16)f.y;
        tile[r][cc + v * 4 + 2] = (bf16)f.z;
        tile[r][cc + v * 4 + 3] = (bf16)f.w;
    }
    __syncthreads();
    bf16x8 o0, o1;
#pragma unroll
    for (int j = 0; j < 8; ++j) { o0[j] = tile[cc + j][r]; o1[j] = tile[cc + 8 + j][r]; }
    bf16* dst = out + (size_t)(c0 + r) * CDIM + r0 + cc;
    *reinterpret_cast<bf16x8*>(dst) = o0;
    *reinterpret_cast<bf16x8*>(dst + 8) = o1;
}

// ---------------------------------------------------------------------------
// 3) QKV GEMM with global_load_lds staging. Swapped-operand mfma so output
//    cols are lane-contiguous (reg dim = 4 consecutive cols).
//    Outputs: Q row-major [bh][s][64]; K,V in attention FRAGMENT order:
//    per (bh, 64-kv tile) 4096 bf16:
//      K elem (s,d): ((kt*4+kb)*64 + hi*32 + l31)*8 + j
//         kt=(s>>5)&1, l31=s&31, kb=d>>4, hi=(d>>3)&1, j=d&7
//      V elem (s,d): ((dt*4+kvb)*64 + hh*32 + (d&31))*8 + jv
//         dt=d>>5, kvb=(s&63)>>4, hh=(s>>3)&1, jv=s&7
__global__ __launch_bounds__(256) void k_gemm_qkv(const bf16* __restrict__ A,
                                                  const bf16* __restrict__ Wt,
                                                  bf16* __restrict__ Qg,
                                                  bf16* __restrict__ Kf,
                                                  bf16* __restrict__ Vf) {
    __shared__ __align__(16) bf16 As[2][4096];
    __shared__ __align__(16) bf16 Bs[2][4096];
    const int id = blockIdx.x;
    const int swz = (id & 7) * 96 + (id >> 3);           // 768 blocks, bijective
    const int mt = swz & 63, r2 = swz >> 6;
    const int nt = r2 & 3, z = r2 >> 2;
    const int m0 = mt * 128, n0 = nt * 128;
    const int t = threadIdx.x, lane = t & 63, wid = t >> 6;
    const int wr = wid >> 1, wc = wid & 1;
    const int q = lane & 15, g = lane >> 4;
    const bf16* Bmat = Wt + (size_t)z * 262144;
    const int srow = lane >> 2, scol = (lane & 3) * 8;

    auto stage = [&](int buf, int kt) {
        const int k0 = kt * 32;
        const bf16* a0 = A + (size_t)(m0 + wid * 32 + srow) * CDIM + k0 + scol;
        glds16(a0,             &As[buf][wid * 1024]);
        glds16(a0 + 16 * CDIM, &As[buf][wid * 1024 + 512]);
        const bf16* b0 = Bmat + (size_t)(n0 + wid * 32 + srow) * CDIM + k0 + scol;
        glds16(b0,             &Bs[buf][wid * 1024]);
        glds16(b0 + 16 * CDIM, &Bs[buf][wid * 1024 + 512]);
    };

    f32x4 acc[4][4] = {};
    stage(0, 0);
    for (int kt = 0; kt < 16; ++kt) {
        const int cur = kt & 1;
        if (kt < 15) { stage(cur ^ 1, kt + 1); wait_vm4(); } else wait_vm0();
        __syncthreads();
        bf16x8 af[4], bfv[4];
#pragma unroll
        for (int m = 0; m < 4; ++m)
            af[m] = *(const bf16x8*)&As[cur][(wr * 64 + m * 16 + q) * 32 + g * 8];
#pragma unroll
        for (int n = 0; n < 4; ++n)
            bfv[n] = *(const bf16x8*)&Bs[cur][(wc * 64 + n * 16 + q) * 32 + g * 8];
#pragma unroll
        for (int m = 0; m < 4; ++m)
#pragma unroll
            for (int n = 0; n < 4; ++n)
                acc[m][n] = __builtin_amdgcn_mfma_f32_16x16x32_bf16(bfv[n], af[m], acc[m][n], 0, 0, 0);
        __syncthreads();
    }
    // D[colsub = g*4+reg][rowsub = q]
#pragma unroll
    for (int m = 0; m < 4; ++m) {
        const int row = m0 + wr * 64 + m * 16 + q;
        const int b = row >> 11, s = row & 2047;
#pragma unroll
        for (int n = 0; n < 4; ++n) {
            const int cb = n0 + wc * 64 + n * 16 + g * 4;
            const size_t bh = (size_t)b * HEADS + (cb >> 6);
            const int d0 = cb & 63;
            const f32x4 v = acc[m][n];
            if (z == 0) {
                uint2 u; u.x = pk_bf16(v[0], v[1]); u.y = pk_bf16(v[2], v[3]);
                *(uint2*)&Qg[(bh * SEQ + s) * 64 + d0] = u;
            } else if (z == 1) {
                const int tile = s >> 6, ktt = (s >> 5) & 1, l31 = s & 31;
                const int kb = d0 >> 4, hh = (d0 >> 3) & 1, j = d0 & 7;
                uint2 u; u.x = pk_bf16(v[0], v[1]); u.y = pk_bf16(v[2], v[3]);
                *(uint2*)&Kf[(bh * 32 + tile) * 4096 +
                             (size_t)(((ktt * 4 + kb) * 64 + hh * 32 + l31) * 8 + j)] = u;
            } else {
                const int tile = s >> 6, kvb = (s & 63) >> 4, hh = (s >> 3) & 1, jv = s & 7;
                const int dt = d0 >> 5;
                const size_t base = (bh * 32 + tile) * 4096;
#pragma unroll
                for (int i = 0; i < 4; ++i) {
                    const int l31v = (d0 + i) & 31;
                    Vf[base + (size_t)(((dt * 4 + kvb) * 64 + hh * 32 + l31v) * 8 + jv)] = (bf16)v[i];
                }
            }
        }
    }
}

// ---------------------------------------------------------------------------
// 4) Flash attention. 4 waves x 32 q (QBLK=128), KVBLK=64.
//    Swapped QK^T with 32x32x16: S^T[kv][q] = mfma(K_frag, Q_frag);
//    lane holds q=lane&31, kv rows = (reg&3)+8*(reg>>2)+4*hi.
//    In-register P via cvt_pk_bf16 + permlane32_swap (T12), defer-max (T13),
//    frag-order LDS staged by global_load_lds, double-buffered, vmcnt(4).
__global__ __launch_bounds__(256) void k_attn(const bf16* __restrict__ Qg,
                                              const bf16* __restrict__ Kf,
                                              const bf16* __restrict__ Vf,
                                              bf16* __restrict__ Og) {
    __shared__ __align__(16) bf16 KV[2][2][4096];   // [buf][K/V][frag order]
    const int id = blockIdx.x;
    const int swz = (id & 7) * 64 + (id >> 3);       // 512 blocks, bijective
    const int bh = swz >> 4, qb = swz & 15;
    const int t = threadIdx.x, lane = t & 63, wid = t >> 6;
    const int q = lane & 31, hi = lane >> 5;
    const int q0 = qb * 128 + wid * 32;
    const int b = bh >> 3, h = bh & 7;

    bf16x8 qf[4];
#pragma unroll
    for (int kb = 0; kb < 4; ++kb)
        qf[kb] = *(const bf16x8*)&Qg[((size_t)bh * SEQ + q0 + q) * 64 + kb * 16 + hi * 8];

    f32x16 oacc[2] = {};
    float m_run = -1e30f, l_run = 0.f;

    auto stage = [&](int buf, int kt) {
        const bf16* kb_ = Kf + ((size_t)bh * 32 + kt) * 4096;
        const bf16* vb_ = Vf + ((size_t)bh * 32 + kt) * 4096;
        const int g0 = wid * 2;
        glds16(kb_ + g0 * 512 + lane * 8,       &KV[buf][0][g0 * 512]);
        glds16(kb_ + (g0 + 1) * 512 + lane * 8, &KV[buf][0][(g0 + 1) * 512]);
        glds16(vb_ + g0 * 512 + lane * 8,       &KV[buf][1][g0 * 512]);
        glds16(vb_ + (g0 + 1) * 512 + lane * 8, &KV[buf][1][(g0 + 1) * 512]);
    };

    stage(0, 0);
    for (int kt = 0; kt < 32; ++kt) {
        const int cur = kt & 1;
        if (kt < 31) { stage(cur ^ 1, kt + 1); wait_vm4(); } else wait_vm0();
        __syncthreads();

        // --- QK^T ---
        f32x16 sa[2] = {};
        __builtin_amdgcn_s_setprio(1);
#pragma unroll
        for (int kt2 = 0; kt2 < 2; ++kt2)
#pragma unroll
            for (int kb = 0; kb < 4; ++kb) {
                bf16x8 kfr = *(const bf16x8*)&KV[cur][0][((kt2 * 4 + kb) * 64 + lane) * 8];
                sa[kt2] = __builtin_amdgcn_mfma_f32_32x32x16_bf16(kfr, qf[kb], sa[kt2], 0, 0, 0);
            }
        __builtin_amdgcn_s_setprio(0);

        // --- online softmax (raw scores; scale folded into exp2) ---
        float m8[8];
#pragma unroll
        for (int r = 0; r < 8; ++r)
            m8[r] = fmaxf(fmaxf(sa[0][r], sa[0][r + 8]), fmaxf(sa[1][r], sa[1][r + 8]));
#pragma unroll
        for (int r = 0; r < 4; ++r) m8[r] = fmaxf(m8[r], m8[r + 4]);
        float tmax = fmaxf(fmaxf(m8[0], m8[1]), fmaxf(m8[2], m8[3]));
        tmax = fmaxf(tmax, __shfl_xor(tmax, 32));

        if (__any(tmax > m_run + THR_RAW)) {        // defer-max: rescale rarely
            const float mnew = fmaxf(m_run, tmax);
            const float al = exp2f((m_run - mnew) * C2);
            l_run *= al;
#pragma unroll
            for (int dt = 0; dt < 2; ++dt)
#pragma unroll
                for (int r = 0; r < 16; ++r) oacc[dt][r] *= al;
            m_run = mnew;
        }
        const float msc = m_run * C2;
#pragma unroll
        for (int kt2 = 0; kt2 < 2; ++kt2)
#pragma unroll
            for (int r = 0; r < 16; ++r)
                sa[kt2][r] = exp2f(fmaf(sa[kt2][r], C2, -msc));

        float s0 = 0.f, s1 = 0.f, s2 = 0.f, s3 = 0.f;
#pragma unroll
        for (int r = 0; r < 16; r += 4) {
            s0 += sa[0][r]     + sa[1][r];
            s1 += sa[0][r + 1] + sa[1][r + 1];
            s2 += sa[0][r + 2] + sa[1][r + 2];
            s3 += sa[0][r + 3] + sa[1][r + 3];
        }
        float psum = (s0 + s1) + (s2 + s3);
        psum += __shfl_xor(psum, 32);
        l_run += psum;

        // --- pack P -> PV B-frags (in-register, T12) ---
        bf16x8 pb[4];
#pragma unroll
        for (int kt2 = 0; kt2 < 2; ++kt2)
#pragma unroll
            for (int b2 = 0; b2 < 2; ++b2) {
                uint32_t lo0 = pk_bf16(sa[kt2][8 * b2 + 0], sa[kt2][8 * b2 + 1]);
                uint32_t lo1 = pk_bf16(sa[kt2][8 * b2 + 2], sa[kt2][8 * b2 + 3]);
                uint32_t hi0 = pk_bf16(sa[kt2][8 * b2 + 4], sa[kt2][8 * b2 + 5]);
                uint32_t hi1 = pk_bf16(sa[kt2][8 * b2 + 6], sa[kt2][8 * b2 + 7]);
                pl_swap(lo0, hi0); pl_swap(lo1, hi1);
                union { uint32_t w[4]; bf16x8 v; } u;
                u.w[0] = lo0; u.w[1] = lo1; u.w[2] = hi0; u.w[3] = hi1;
                pb[kt2 * 2 + b2] = u.v;
            }

        // --- PV: O^T[d][q] += V^T frag x P frag ---
        __builtin_amdgcn_s_setprio(1);
#pragma unroll
        for (int dt = 0; dt < 2; ++dt)
#pragma unroll
            for (int bb = 0; bb < 4; ++bb) {
                bf16x8 vfr = *(const bf16x8*)&KV[cur][1][((dt * 4 + bb) * 64 + lane) * 8];
                oacc[dt] = __builtin_amdgcn_mfma_f32_32x32x16_bf16(vfr, pb[bb], oacc[dt], 0, 0, 0);
            }
        __builtin_amdgcn_s_setprio(0);
        __syncthreads();
    }

    const float inv = 1.0f / l_run;
    bf16* orow = Og + ((size_t)b * SEQ + q0 + q) * CDIM + h * 64;
#pragma unroll
    for (int dt = 0; dt < 2; ++dt)
#pragma unroll
        for (int rr = 0; rr < 4; ++rr) {
            const int d0 = dt * 32 + rr * 8 + hi * 4;
            uint2 u;
            u.x = pk_bf16(oacc[dt][4 * rr] * inv,     oacc[dt][4 * rr + 1] * inv);
            u.y = pk_bf16(oacc[dt][4 * rr + 2] * inv, oacc[dt][4 * rr + 3] * inv);
            *(uint2*)&orow[d0] = u;
        }
}

// ---------------------------------------------------------------------------
// 5) Output GEMM: Og[8192][512]bf16 x Wo_t[512][512]bf16 -> out f32.
//    128x64 tiles (512 blocks), swapped-operand epilogue -> float4 stores.
__global__ __launch_bounds__(256) void k_gemm_o(const bf16* __restrict__ A,
                                                const bf16* __restrict__ Bt,
                                                float* __restrict__ out) {
    __shared__ __align__(16) bf16 As[2][4096];
    __shared__ __align__(16) bf16 Bs[2][2048];
    const int id = blockIdx.x;
    const int swz = (id & 7) * 64 + (id >> 3);       // 512 blocks, bijective
    const int mt = swz & 63, nt = swz >> 6;
    const int m0 = mt * 128, n0 = nt * 64;
    const int t = threadIdx.x, lane = t & 63, wid = t >> 6;
    const int wr = wid >> 1, wc = wid & 1;
    const int q = lane & 15, g = lane >> 4;
    const int srow = lane >> 2, scol = (lane & 3) * 8;

    auto stage = [&](int buf, int kt) {
        const int k0 = kt * 32;
        const bf16* a0 = A + (size_t)(m0 + wid * 32 + srow) * CDIM + k0 + scol;
        glds16(a0,             &As[buf][wid * 1024]);
        glds16(a0 + 16 * CDIM, &As[buf][wid * 1024 + 512]);
        const bf16* b0 = Bt + (size_t)(n0 + wid * 16 + srow) * CDIM + k0 + scol;
        glds16(b0, &Bs[buf][wid * 512]);
    };

    f32x4 acc[4][2] = {};
    stage(0, 0);
    for (int kt = 0; kt < 16; ++kt) {
        const int cur = kt & 1;
        if (kt < 15) { stage(cur ^ 1, kt + 1); wait_vm3(); } else wait_vm0();
        __syncthreads();
        bf16x8 af[4], bfv[2];
#pragma unroll
        for (int m = 0; m < 4; ++m)
            af[m] = *(const bf16x8*)&As[cur][(wr * 64 + m * 16 + q) * 32 + g * 8];
#pragma unroll
        for (int n = 0; n < 2; ++n)
            bfv[n] = *(const bf16x8*)&Bs[cur][(wc * 32 + n * 16 + q) * 32 + g * 8];
#pragma unroll
        for (int m = 0; m < 4; ++m)
#pragma unroll
            for (int n = 0; n < 2; ++n)
                acc[m][n] = __builtin_amdgcn_mfma_f32_16x16x32_bf16(bfv[n], af[m], acc[m][n], 0, 0, 0);
        __syncthreads();
    }
#pragma unroll
    for (int m = 0; m < 4; ++m) {
        const int row = m0 + wr * 64 + m * 16 + q;
#pragma unroll
        for (int n = 0; n < 2; ++n) {
            const int cb = n0 + wc * 32 + n * 16 + g * 4;
            *(f32x4*)&out[(size_t)row * CDIM + cb] = acc[m][n];
        }
    }
}

// ---------------------------------------------------------------------------
extern "C" void kernel_launch(void* const* d_in, const int* in_sizes, int n_in,
                              void* d_out, int out_size, void* d_ws, size_t ws_size,
                              hipStream_t stream) {
    const float* hs = (const float*)d_in[0];
    const float* Wq = (const float*)d_in[1];
    const float* Wk = (const float*)d_in[2];
    const float* Wv = (const float*)d_in[3];
    const float* Wo = (const float*)d_in[4];
    float* out = (float*)d_out;

    bf16* hs_bf = (bf16*)d_ws;                 //  8 MB  (8192x512)
    bf16* wt    = hs_bf + 4194304;             //  2 MB  (4 x 512x512, [fout][fin])
    bf16* Qg    = wt + 1048576;                //  8 MB  [bh][s][64]
    bf16* Kf    = Qg + 4194304;                //  8 MB  frag-order
    bf16* Vf    = Kf + 4194304;                //  8 MB  frag-order
    bf16* Og    = Vf + 4194304;                //  8 MB  [b][s][512]

    k_cvt_hs<<<2048, 256, 0, stream>>>(hs, hs_bf);
    k_wtrans<<<dim3(8, 8, 4), 256, 0, stream>>>(Wq, Wk, Wv, Wo, wt);
    k_gemm_qkv<<<768, 256, 0, stream>>>(hs_bf, wt, Qg, Kf, Vf);
    k_attn<<<512, 256, 0, stream>>>(Qg, Kf, Vf, Og);
    k_gemm_o<<<512, 256, 0, stream>>>(Og, wt + 3 * 262144, out);
}